// Round 1
// baseline (93.418 us; speedup 1.0000x reference)
//
#include <hip/hip_runtime.h>
#include <cstdint>

// LIERE position encoder: batched expm of 8x8 skew-symmetric matrices.
// out[n][l][g][i][j] = expm( p0(n)*B0[l,g] + p1(n)*B1[l,g] )[i][j]
// n=0 is the cls token -> identity. B_d strict-upper = gen_params[d], skew.
constexpr int LG   = 512;       // 4 layers * 128 generators
constexpr int NPOS = 1025;      // 1024 patches + cls
constexpr int NMAT = NPOS * LG; // 524800

__global__ __launch_bounds__(256)
void liere_expm_kernel(const float* __restrict__ pos,   // [1,1024,2]
                       const float* __restrict__ gen,   // [2,4,128,8,8]
                       float* __restrict__ out)         // [1,1025,4,128,8,8]
{
    int m = blockIdx.x * blockDim.x + threadIdx.x;
    if (m >= NMAT) return;
    int n  = m >> 9;       // token index 0..1024
    int lg = m & 511;      // l*128+g
    float* o = out + (size_t)m * 64;

    float S[64];           // result accumulator

    if (n == 0) {
        #pragma unroll
        for (int i = 0; i < 8; ++i)
            #pragma unroll
            for (int j = 0; j < 8; ++j)
                S[i*8+j] = (i == j) ? 1.f : 0.f;
    } else {
        float p0 = pos[(n-1)*2 + 0];
        float p1 = pos[(n-1)*2 + 1];
        const float* g0 = gen + (size_t)lg * 64;           // d=0
        const float* g1 = g0 + (size_t)LG * 64;            // d=1

        // Build X = p0*B0 + p1*B1 (skew-symmetric; -0.5 shift cancels)
        float X[64];
        #pragma unroll
        for (int i = 0; i < 8; ++i) X[i*8+i] = 0.f;
        #pragma unroll
        for (int i = 0; i < 8; ++i)
            #pragma unroll
            for (int j = i+1; j < 8; ++j) {
                float v = fmaf(p0, g0[i*8+j], p1 * g1[i*8+j]);
                X[i*8+j] = v;
                X[j*8+i] = -v;
            }

        // inf-norm (max abs row sum)
        float nrm = 0.f;
        #pragma unroll
        for (int i = 0; i < 8; ++i) {
            float rs = 0.f;
            #pragma unroll
            for (int j = 0; j < 8; ++j) rs += fabsf(X[i*8+j]);
            nrm = fmaxf(nrm, rs);
        }
        // scaling: s = ilogb(nrm)+3  =>  ||X/2^s|| <= 0.25
        uint32_t ub = __float_as_uint(nrm);
        int e = (int)((ub >> 23) & 255) - 127;
        int s = e + 3; if (s < 0) s = 0;
        float scale = __uint_as_float((uint32_t)(127 - s) << 23);
        #pragma unroll
        for (int k = 0; k < 64; ++k) X[k] *= scale;

        // Taylor degree 6 via Horner: S_6 = I + X/6; S_{k} = I + X*S_{k+1}/k
        #pragma unroll
        for (int k = 0; k < 64; ++k) S[k] = X[k] * (1.f/6.f);
        #pragma unroll
        for (int i = 0; i < 8; ++i) S[i*8+i] += 1.f;

        #pragma unroll
        for (int kk = 5; kk >= 1; --kk) {
            float inv = 1.f / (float)kk;   // compile-time constant (unrolled)
            float T[64];
            #pragma unroll
            for (int i = 0; i < 8; ++i)
                #pragma unroll
                for (int j = 0; j < 8; ++j) {
                    float acc = 0.f;
                    #pragma unroll
                    for (int k = 0; k < 8; ++k)
                        acc = fmaf(X[i*8+k], S[k*8+j], acc);
                    T[i*8+j] = acc;
                }
            #pragma unroll
            for (int t = 0; t < 64; ++t) S[t] = fmaf(T[t], inv, 0.f);
            #pragma unroll
            for (int i = 0; i < 8; ++i) S[i*8+i] += 1.f;
        }

        // s squarings: S <- S*S
        for (int q = 0; q < s; ++q) {
            float T[64];
            #pragma unroll
            for (int i = 0; i < 8; ++i)
                #pragma unroll
                for (int j = 0; j < 8; ++j) {
                    float acc = 0.f;
                    #pragma unroll
                    for (int k = 0; k < 8; ++k)
                        acc = fmaf(S[i*8+k], S[k*8+j], acc);
                    T[i*8+j] = acc;
                }
            #pragma unroll
            for (int t = 0; t < 64; ++t) S[t] = T[t];
        }
    }

    // contiguous 256B per-thread store, 16x float4
    float4* o4 = reinterpret_cast<float4*>(o);
    #pragma unroll
    for (int k = 0; k < 16; ++k)
        o4[k] = make_float4(S[4*k+0], S[4*k+1], S[4*k+2], S[4*k+3]);
}

extern "C" void kernel_launch(void* const* d_in, const int* in_sizes, int n_in,
                              void* d_out, int out_size, void* d_ws, size_t ws_size,
                              hipStream_t stream) {
    const float* pos = (const float*)d_in[0];   // positions [1,1024,2]
    const float* gen = (const float*)d_in[1];   // gen_params [2,4,128,8,8]
    float* out = (float*)d_out;                 // [1,1025,4,128,8,8] fp32

    int block = 256;
    int grid  = (NMAT + block - 1) / block;     // 2050 blocks
    liere_expm_kernel<<<grid, block, 0, stream>>>(pos, gen, out);
}

// Round 2
// 83.556 us; speedup vs baseline: 1.1180x; 1.1180x over previous
//
#include <hip/hip_runtime.h>
#include <cstdint>

// LIERE position encoder: batched expm of 8x8 skew-symmetric matrices.
// out[n][l][g] = expm( p0(n)*B0[l,g] + p1(n)*B1[l,g] ), n=0 -> identity.
constexpr int LG   = 512;       // 4 layers * 128 generators
constexpr int NPOS = 1025;      // 1024 patches + cls
constexpr int NMAT = NPOS * LG; // 524800

__global__ __launch_bounds__(256)
void liere_expm_kernel(const float* __restrict__ pos,   // [1,1024,2]
                       const float* __restrict__ gen,   // [2,4,128,8,8]
                       float* __restrict__ out)         // [1,1025,4,128,8,8]
{
    int m = blockIdx.x * blockDim.x + threadIdx.x;
    if (m >= NMAT) return;
    int n  = m >> 9;       // token index 0..1024 (uniform per block)
    int lg = m & 511;      // l*128+g
    float4* o4 = reinterpret_cast<float4*>(out + (size_t)m * 64);

    if (n == 0) {          // cls token -> identity (blocks 0,1 entirely)
        #pragma unroll
        for (int k = 0; k < 16; ++k) {
            int r = k >> 1;            // row
            int c0 = (k & 1) * 4;      // col of first elem
            o4[k] = make_float4(r==c0?1.f:0.f, r==c0+1?1.f:0.f,
                                r==c0+2?1.f:0.f, r==c0+3?1.f:0.f);
        }
        return;
    }

    float p0 = pos[(n-1)*2 + 0];
    float p1 = pos[(n-1)*2 + 1];
    const float* g0 = gen + (size_t)lg * 64;           // d=0
    const float* g1 = g0 + (size_t)LG * 64;            // d=1

    // X = p0*B0 + p1*B1 (skew-symmetric; the -0.5 shift cancels), UNscaled
    float X[64];
    #pragma unroll
    for (int i = 0; i < 8; ++i) X[i*8+i] = 0.f;
    #pragma unroll
    for (int i = 0; i < 8; ++i)
        #pragma unroll
        for (int j = i+1; j < 8; ++j) {
            float v = fmaf(p0, g0[i*8+j], p1 * g1[i*8+j]);
            X[i*8+j] = v;
            X[j*8+i] = -v;
        }

    // Y = X*X  (reused for both the norm bound and the Taylor seed)
    float P[64];
    #pragma unroll
    for (int i = 0; i < 8; ++i)
        #pragma unroll
        for (int j = 0; j < 8; ++j) {
            float acc = X[i*8+0] * X[0*8+j];
            #pragma unroll
            for (int k = 1; k < 8; ++k)
                acc = fmaf(X[i*8+k], X[k*8+j], acc);
            P[i*8+j] = acc;   // P currently holds Y
        }

    // theta^2 = rho(Y) <= ||Y||_inf  (Y symmetric)
    float yb = 0.f;
    #pragma unroll
    for (int i = 0; i < 8; ++i) {
        float rs = fabsf(P[i*8+0]);
        #pragma unroll
        for (int j = 1; j < 8; ++j) rs += fabsf(P[i*8+j]);
        yb = fmaxf(yb, rs);
    }
    // s = ceil(log2(2*sqrt(yb))) so that theta/2^s <= 0.5
    uint32_t u = __float_as_uint(yb);
    int e2 = (int)((u >> 23) & 255) - 127;
    int L  = e2 + 2 + (((u & 0x7fffffu) != 0u) ? 1 : 0);  // ceil(log2(4*yb))
    int s  = (L + 1) >> 1;
    if (s < 0) s = 0;

    // wave-uniform s (scaling extra for small-norm lanes is exact math)
    #pragma unroll
    for (int off = 32; off >= 1; off >>= 1) {
        int t = __shfl_xor(s, off, 64);
        s = (t > s) ? t : s;
    }

    float sc1 = __uint_as_float((uint32_t)(127 - s)  << 23);   // 2^-s
    float sc2 = __uint_as_float((uint32_t)(127 - 2*s) << 23);  // 2^-2s
    #pragma unroll
    for (int k = 0; k < 64; ++k) X[k] *= sc1;

    // Horner seed: P = (1/720)*Ys + (1/120)*Xs + (1/24)*I   (Ys = sc2*Y)
    const float c6s = (1.f/720.f);
    #pragma unroll
    for (int k = 0; k < 64; ++k)
        P[k] = fmaf(c6s * sc2, P[k], (1.f/120.f) * X[k]);
    #pragma unroll
    for (int i = 0; i < 8; ++i) P[i*8+i] += (1.f/24.f);

    // 4 Horner steps: P <- P*X + c*I  for c = 1/6, 1/2, 1, 1  (in place by rows)
    #pragma unroll
    for (int step = 0; step < 4; ++step) {
        const float c = (step == 0) ? (1.f/6.f) : (step == 1) ? 0.5f : 1.f;
        #pragma unroll
        for (int i = 0; i < 8; ++i) {
            float a0=P[i*8+0], a1=P[i*8+1], a2=P[i*8+2], a3=P[i*8+3];
            float a4=P[i*8+4], a5=P[i*8+5], a6=P[i*8+6], a7=P[i*8+7];
            #pragma unroll
            for (int j = 0; j < 8; ++j) {
                float acc = a0 * X[0*8+j];
                acc = fmaf(a1, X[1*8+j], acc);
                acc = fmaf(a2, X[2*8+j], acc);
                acc = fmaf(a3, X[3*8+j], acc);
                acc = fmaf(a4, X[4*8+j], acc);
                acc = fmaf(a5, X[5*8+j], acc);
                acc = fmaf(a6, X[6*8+j], acc);
                acc = fmaf(a7, X[7*8+j], acc);
                P[i*8+j] = acc;
            }
            P[i*8+i] += c;
        }
    }

    // s squarings, ping-pong (s is wave-uniform -> scalar loop, no masking)
    {
        float Q[64];
        int q = s;
        while (q >= 2) {
            #pragma unroll
            for (int i = 0; i < 8; ++i)
                #pragma unroll
                for (int j = 0; j < 8; ++j) {
                    float acc = P[i*8+0] * P[0*8+j];
                    #pragma unroll
                    for (int k = 1; k < 8; ++k)
                        acc = fmaf(P[i*8+k], P[k*8+j], acc);
                    Q[i*8+j] = acc;
                }
            #pragma unroll
            for (int i = 0; i < 8; ++i)
                #pragma unroll
                for (int j = 0; j < 8; ++j) {
                    float acc = Q[i*8+0] * Q[0*8+j];
                    #pragma unroll
                    for (int k = 1; k < 8; ++k)
                        acc = fmaf(Q[i*8+k], Q[k*8+j], acc);
                    P[i*8+j] = acc;
                }
            q -= 2;
        }
        if (q) {
            #pragma unroll
            for (int i = 0; i < 8; ++i)
                #pragma unroll
                for (int j = 0; j < 8; ++j) {
                    float acc = P[i*8+0] * P[0*8+j];
                    #pragma unroll
                    for (int k = 1; k < 8; ++k)
                        acc = fmaf(P[i*8+k], P[k*8+j], acc);
                    Q[i*8+j] = acc;
                }
            #pragma unroll
            for (int t = 0; t < 64; ++t) P[t] = Q[t];
        }
    }

    #pragma unroll
    for (int k = 0; k < 16; ++k)
        o4[k] = make_float4(P[4*k+0], P[4*k+1], P[4*k+2], P[4*k+3]);
}

extern "C" void kernel_launch(void* const* d_in, const int* in_sizes, int n_in,
                              void* d_out, int out_size, void* d_ws, size_t ws_size,
                              hipStream_t stream) {
    const float* pos = (const float*)d_in[0];   // positions [1,1024,2]
    const float* gen = (const float*)d_in[1];   // gen_params [2,4,128,8,8]
    float* out = (float*)d_out;                 // [1,1025,4,128,8,8] fp32

    int block = 256;
    int grid  = (NMAT + block - 1) / block;     // 2050 blocks
    liere_expm_kernel<<<grid, block, 0, stream>>>(pos, gen, out);
}

// Round 3
// 76.429 us; speedup vs baseline: 1.2223x; 1.0932x over previous
//
#include <hip/hip_runtime.h>
#include <cstdint>

// LIERE position encoder: batched expm of 8x8 skew-symmetric matrices.
// exp(X) = E(Y) + X*O(Y), Y = X^2 (symmetric), E,O symmetric polys in Y.
constexpr int LG   = 512;       // 4 layers * 128 generators
constexpr int NPOS = 1025;      // 1024 patches + cls
constexpr int NMAT = NPOS * LG; // 524800
constexpr int GEN_ELEMS = 2 * LG * 64;   // 65536 floats = 256 KB

__host__ __device__ constexpr int UI(int i, int j) { // strict upper (i<j) -> 0..27
    return i*7 - (i*(i-1))/2 + (j - i - 1);
}
__host__ __device__ constexpr int SI(int i, int j) { // sym (i<=j) -> 0..35
    return i*8 - (i*(i-1))/2 + (j - i);
}

// symmetric accessors (indices are compile-time constants after unroll)
#define YSsym(a,b)  Ys [ (a)<=(b) ? SI(a,b) : SI(b,a) ]
#define Y2sym(a,b)  Y2s[ (a)<=(b) ? SI(a,b) : SI(b,a) ]
#define Zsym(a,b)   Zs [ (a)<=(b) ? SI(a,b) : SI(b,a) ]
#define Esym(a,b)   Es [ (a)<=(b) ? SI(a,b) : SI(b,a) ]
// skew X from upper values (valid only for i!=k)
#define XV(i,k) ( (i)<(k) ? U[UI(i,k)] : -U[UI(k,i)] )

__device__ __forceinline__ void sq64(float (&D)[64], const float (&S)[64]) {
    #pragma unroll
    for (int i = 0; i < 8; ++i)
        #pragma unroll
        for (int j = 0; j < 8; ++j) {
            float acc = S[i*8+0] * S[0*8+j];
            #pragma unroll
            for (int k = 1; k < 8; ++k)
                acc = fmaf(S[i*8+k], S[k*8+j], acc);
            D[i*8+j] = acc;
        }
}

__device__ __forceinline__ void store64(float4* o4, const float (&R)[64]) {
    #pragma unroll
    for (int k = 0; k < 16; ++k)
        o4[k] = make_float4(R[4*k+0], R[4*k+1], R[4*k+2], R[4*k+3]);
}

// transpose gen [2][512][64] -> genT [64][512][2]  (coalesced per-lane float2)
__global__ __launch_bounds__(256)
void liere_tr_kernel(const float* __restrict__ g, float* __restrict__ gT) {
    int t = blockIdx.x * 256 + threadIdx.x;
    if (t >= GEN_ELEMS) return;
    int d  = t >> 15;
    int lg = (t >> 6) & 511;
    int e  = t & 63;
    gT[(size_t)e * 1024 + lg * 2 + d] = g[t];
}

template<bool TR>
__global__ __launch_bounds__(256)
void liere_expm_kernel(const float* __restrict__ pos,   // [1,1024,2]
                       const float* __restrict__ gen,   // [2,4,128,8,8]
                       const float* __restrict__ genT,  // [64,512,2] (if TR)
                       float* __restrict__ out)         // [1,1025,4,128,8,8]
{
    const int bid = blockIdx.x, tid = threadIdx.x;
    const int n   = bid >> 1;                    // token index, block-uniform
    const int lg  = ((bid & 1) << 8) | tid;
    float4* o4 = reinterpret_cast<float4*>(out + (size_t)(bid * 256 + tid) * 64);

    if (n == 0) {   // cls -> identity (blocks 0,1, uniform branch)
        #pragma unroll
        for (int k = 0; k < 16; ++k) {
            int r = k >> 1, c0 = (k & 1) * 4;
            o4[k] = make_float4((float)(r==c0), (float)(r==c0+1),
                                (float)(r==c0+2), (float)(r==c0+3));
        }
        return;
    }

    const float p0 = pos[(n-1)*2 + 0];   // block-uniform -> scalar loads
    const float p1 = pos[(n-1)*2 + 1];

    // ---- build strict-upper of X = p0*B0 + p1*B1 (the -0.5 shift cancels) ----
    float U[28];
    if (TR) {
        #pragma unroll
        for (int i = 0; i < 8; ++i)
            #pragma unroll
            for (int j = i+1; j < 8; ++j) {
                const int e = i*8 + j;
                float2 v = *reinterpret_cast<const float2*>(
                               genT + (size_t)e * 1024 + lg * 2);
                U[UI(i,j)] = fmaf(p0, v.x, p1 * v.y);
            }
    } else {
        const float* g0 = gen + (size_t)lg * 64;
        const float* g1 = g0 + (size_t)LG * 64;
        #pragma unroll
        for (int i = 0; i < 8; ++i)
            #pragma unroll
            for (int j = i+1; j < 8; ++j) {
                const int e = i*8 + j;
                U[UI(i,j)] = fmaf(p0, g0[e], p1 * g1[e]);
            }
    }

    // ---- Y = X^2 (symmetric, 36 entries; X diag is 0) ----
    float Ys[36];
    #pragma unroll
    for (int i = 0; i < 8; ++i)
        #pragma unroll
        for (int j = i; j < 8; ++j) {
            float acc = 0.f;
            #pragma unroll
            for (int k = 0; k < 8; ++k) {
                if (k == i || k == j) continue;
                acc = fmaf(XV(i,k), XV(k,j), acc);
            }
            Ys[SI(i,j)] = acc;
        }

    // ---- Y2 = Y^2 (symmetric) ----
    float Y2s[36];
    #pragma unroll
    for (int i = 0; i < 8; ++i)
        #pragma unroll
        for (int j = i; j < 8; ++j) {
            float acc = YSsym(i,0) * YSsym(0,j);
            #pragma unroll
            for (int k = 1; k < 8; ++k)
                acc = fmaf(YSsym(i,k), YSsym(k,j), acc);
            Y2s[SI(i,j)] = acc;
        }

    // ---- theta^4 <= ||Y2||_inf ; s = ceil(log2(theta) - log2(1.15)) ----
    float yb = 0.f;
    #pragma unroll
    for (int i = 0; i < 8; ++i) {
        float rs = fabsf(Y2sym(i,0));
        #pragma unroll
        for (int j = 1; j < 8; ++j) rs += fabsf(Y2sym(i,j));
        yb = fmaxf(yb, rs);
    }
    #pragma unroll
    for (int off = 32; off >= 1; off >>= 1)
        yb = fmaxf(yb, __shfl_xor(yb, off, 64));
    int s = (int)ceilf(0.25f * __log2f(yb) - 0.2016f);
    if (s < 0) s = 0;
    if (s > 24) s = 24;

    const float r1 = __uint_as_float((uint32_t)(127 - s)   << 23); // 2^-s
    const float r2 = r1 * r1;
    const float r4 = r2 * r2;
    #pragma unroll
    for (int k = 0; k < 28; ++k) U[k]   *= r1;
    #pragma unroll
    for (int k = 0; k < 36; ++k) Ys[k]  *= r2;
    #pragma unroll
    for (int k = 0; k < 36; ++k) Y2s[k] *= r4;

    // ---- Z = Y^3 = Y*Y2 (symmetric: both polys in Y commute) ----
    float Zs[36];
    #pragma unroll
    for (int i = 0; i < 8; ++i)
        #pragma unroll
        for (int j = i; j < 8; ++j) {
            float acc = YSsym(i,0) * Y2sym(0,j);
            #pragma unroll
            for (int k = 1; k < 8; ++k)
                acc = fmaf(YSsym(i,k), Y2sym(k,j), acc);
            Zs[SI(i,j)] = acc;
        }

    // ---- E = I + Y/2 + Y2/24 + Z/720  (deg-7 even part) ----
    float Es[36];
    #pragma unroll
    for (int k = 0; k < 36; ++k)
        Es[k] = fmaf(Zs[k], (1.f/720.f),
                fmaf(Y2s[k], (1.f/24.f), Ys[k] * 0.5f));
    #pragma unroll
    for (int i = 0; i < 8; ++i) Es[SI(i,i)] += 1.f;

    // ---- O = I + Y/6 + Y2/120 + Z/5040  (in place over Z) ----
    #pragma unroll
    for (int k = 0; k < 36; ++k)
        Zs[k] = fmaf(Zs[k], (1.f/5040.f),
                fmaf(Y2s[k], (1.f/120.f), Ys[k] * (1.f/6.f)));
    #pragma unroll
    for (int i = 0; i < 8; ++i) Zs[SI(i,i)] += 1.f;

    // ---- R = E + X*O  (full 8x8; X row has 7 nonzeros) ----
    float R[64];
    #pragma unroll
    for (int i = 0; i < 8; ++i)
        #pragma unroll
        for (int j = 0; j < 8; ++j) {
            float acc = Esym(i,j);
            #pragma unroll
            for (int k = 0; k < 8; ++k) {
                if (k == i) continue;
                acc = fmaf(XV(i,k), Zsym(k,j), acc);
            }
            R[i*8+j] = acc;
        }

    // ---- s squarings (s wave-uniform); parity-aware store, no copies ----
    float Q[64];
    int pairs = s >> 1;
    while (pairs--) { sq64(Q, R); sq64(R, Q); }
    if (s & 1) { sq64(Q, R); store64(o4, Q); }
    else       { store64(o4, R); }
}

extern "C" void kernel_launch(void* const* d_in, const int* in_sizes, int n_in,
                              void* d_out, int out_size, void* d_ws, size_t ws_size,
                              hipStream_t stream) {
    const float* pos = (const float*)d_in[0];   // positions [1,1024,2]
    const float* gen = (const float*)d_in[1];   // gen_params [2,4,128,8,8]
    float* out = (float*)d_out;

    const int block = 256;
    const int grid  = NMAT / block;             // 2050, exact

    if (ws_size >= (size_t)GEN_ELEMS * sizeof(float)) {
        float* genT = (float*)d_ws;
        liere_tr_kernel<<<GEN_ELEMS / 256, 256, 0, stream>>>(gen, genT);
        liere_expm_kernel<true><<<grid, block, 0, stream>>>(pos, gen, genT, out);
    } else {
        liere_expm_kernel<false><<<grid, block, 0, stream>>>(pos, gen, nullptr, out);
    }
}

// Round 4
// 62.525 us; speedup vs baseline: 1.4941x; 1.2224x over previous
//
#include <hip/hip_runtime.h>
#include <cstdint>

// LIERE position encoder: batched expm of 8x8 skew-symmetric matrices.
// exp(X) = E(Y) + X*O(Y), Y = X^2 (symmetric), E,O symmetric polys in Y.
constexpr int LG   = 512;       // 4 layers * 128 generators
constexpr int NPOS = 1025;      // 1024 patches + cls
constexpr int NMAT = NPOS * LG; // 524800
constexpr int GEN_ELEMS = 2 * LG * 64;   // 65536 floats = 256 KB

__host__ __device__ constexpr int UI(int i, int j) { // strict upper (i<j) -> 0..27
    return i*7 - (i*(i-1))/2 + (j - i - 1);
}
__host__ __device__ constexpr int SI(int i, int j) { // sym (i<=j) -> 0..35
    return i*8 - (i*(i-1))/2 + (j - i);
}

#define YSsym(a,b)  Ys [ (a)<=(b) ? SI(a,b) : SI(b,a) ]
#define Y2sym(a,b)  Y2s[ (a)<=(b) ? SI(a,b) : SI(b,a) ]
#define Zsym(a,b)   Zs [ (a)<=(b) ? SI(a,b) : SI(b,a) ]
#define Esym(a,b)   Es [ (a)<=(b) ? SI(a,b) : SI(b,a) ]
#define XV(i,k) ( (i)<(k) ? U[UI(i,k)] : -U[UI(k,i)] )

__device__ __forceinline__ void sq64(float (&D)[64], const float (&S)[64]) {
    #pragma unroll
    for (int i = 0; i < 8; ++i)
        #pragma unroll
        for (int j = 0; j < 8; ++j) {
            float acc = S[i*8+0] * S[0*8+j];
            #pragma unroll
            for (int k = 1; k < 8; ++k)
                acc = fmaf(S[i*8+k], S[k*8+j], acc);
            D[i*8+j] = acc;
        }
}

// transpose gen [2][512][64] -> genT [64][512][2]  (coalesced per-lane float2)
__global__ __launch_bounds__(256)
void liere_tr_kernel(const float* __restrict__ g, float* __restrict__ gT) {
    int t = blockIdx.x * 256 + threadIdx.x;
    if (t >= GEN_ELEMS) return;
    int d  = t >> 15;
    int lg = (t >> 6) & 511;
    int e  = t & 63;
    gT[(size_t)e * 1024 + lg * 2 + d] = g[t];
}

template<bool TR>
__global__ __launch_bounds__(256)
void liere_expm_kernel(const float* __restrict__ pos,   // [1,1024,2]
                       const float* __restrict__ gen,   // [2,4,128,8,8]
                       const float* __restrict__ genT,  // [64,512,2] (if TR)
                       float* __restrict__ out)         // [1,1025,4,128,8,8]
{
    const int bid = blockIdx.x, tid = threadIdx.x;
    const int n   = bid >> 1;                    // token index, block-uniform
    const int lg  = ((bid & 1) << 8) | tid;

    float P[64];   // result

    if (n == 0) {   // cls -> identity (blocks 0,1; block-uniform branch)
        #pragma unroll
        for (int i = 0; i < 8; ++i)
            #pragma unroll
            for (int j = 0; j < 8; ++j)
                P[i*8+j] = (i == j) ? 1.f : 0.f;
    } else {
        const float p0 = pos[(n-1)*2 + 0];   // block-uniform -> scalar loads
        const float p1 = pos[(n-1)*2 + 1];

        // ---- strict-upper of X = p0*B0 + p1*B1 (the -0.5 shift cancels) ----
        float U[28];
        if (TR) {
            #pragma unroll
            for (int i = 0; i < 8; ++i)
                #pragma unroll
                for (int j = i+1; j < 8; ++j) {
                    const int e = i*8 + j;
                    float2 v = *reinterpret_cast<const float2*>(
                                   genT + (size_t)e * 1024 + lg * 2);
                    U[UI(i,j)] = fmaf(p0, v.x, p1 * v.y);
                }
        } else {
            const float* g0 = gen + (size_t)lg * 64;
            const float* g1 = g0 + (size_t)LG * 64;
            #pragma unroll
            for (int i = 0; i < 8; ++i)
                #pragma unroll
                for (int j = i+1; j < 8; ++j) {
                    const int e = i*8 + j;
                    U[UI(i,j)] = fmaf(p0, g0[e], p1 * g1[e]);
                }
        }

        // ---- Y = X^2 (symmetric, 36 entries; X diag is 0) ----
        float Ys[36];
        #pragma unroll
        for (int i = 0; i < 8; ++i)
            #pragma unroll
            for (int j = i; j < 8; ++j) {
                float acc = 0.f;
                #pragma unroll
                for (int k = 0; k < 8; ++k) {
                    if (k == i || k == j) continue;
                    acc = fmaf(XV(i,k), XV(k,j), acc);
                }
                Ys[SI(i,j)] = acc;
            }

        // ---- Y2 = Y^2 (symmetric) ----
        float Y2s[36];
        #pragma unroll
        for (int i = 0; i < 8; ++i)
            #pragma unroll
            for (int j = i; j < 8; ++j) {
                float acc = YSsym(i,0) * YSsym(0,j);
                #pragma unroll
                for (int k = 1; k < 8; ++k)
                    acc = fmaf(YSsym(i,k), YSsym(k,j), acc);
                Y2s[SI(i,j)] = acc;
            }

        // ---- theta^4 <= min(||Y2||_inf, tr(Y^4)/2) ----
        float yb = 0.f, s4 = 0.f;
        #pragma unroll
        for (int i = 0; i < 8; ++i) {
            float rs = 0.f;
            #pragma unroll
            for (int j = 0; j < 8; ++j) {
                float v = Y2sym(i,j);
                rs += fabsf(v);
                s4 = fmaf(v, v, s4);     // accumulates full 64-sum = tr(Y^4)
            }
            yb = fmaxf(yb, rs);
        }
        float q = fminf(yb, 0.5f * s4);
        q = fmaxf(q, 1e-30f);
        #pragma unroll
        for (int off = 32; off >= 1; off >>= 1)
            q = fmaxf(q, __shfl_xor(q, off, 64));
        // s = ceil(log2(theta) - log2(1.3)) ; log2(1.3)=0.3785
        int s = (int)ceilf(0.25f * __log2f(q) - 0.3785f);
        if (s < 0) s = 0;
        if (s > 24) s = 24;

        const float r1 = __uint_as_float((uint32_t)(127 - s)   << 23); // 2^-s
        const float r2 = r1 * r1;
        const float r4 = r2 * r2;
        #pragma unroll
        for (int k = 0; k < 28; ++k) U[k]   *= r1;
        #pragma unroll
        for (int k = 0; k < 36; ++k) Ys[k]  *= r2;
        #pragma unroll
        for (int k = 0; k < 36; ++k) Y2s[k] *= r4;

        // ---- Z = Y^3 = Y*Y2 (symmetric) ----
        float Zs[36];
        #pragma unroll
        for (int i = 0; i < 8; ++i)
            #pragma unroll
            for (int j = i; j < 8; ++j) {
                float acc = YSsym(i,0) * Y2sym(0,j);
                #pragma unroll
                for (int k = 1; k < 8; ++k)
                    acc = fmaf(YSsym(i,k), Y2sym(k,j), acc);
                Zs[SI(i,j)] = acc;
            }

        // ---- E = I + Y/2 + Y2/24 + Z/720 ----
        float Es[36];
        #pragma unroll
        for (int k = 0; k < 36; ++k)
            Es[k] = fmaf(Zs[k], (1.f/720.f),
                    fmaf(Y2s[k], (1.f/24.f), Ys[k] * 0.5f));
        #pragma unroll
        for (int i = 0; i < 8; ++i) Es[SI(i,i)] += 1.f;

        // ---- O = I + Y/6 + Y2/120 + Z/5040 (in place over Z) ----
        #pragma unroll
        for (int k = 0; k < 36; ++k)
            Zs[k] = fmaf(Zs[k], (1.f/5040.f),
                    fmaf(Y2s[k], (1.f/120.f), Ys[k] * (1.f/6.f)));
        #pragma unroll
        for (int i = 0; i < 8; ++i) Zs[SI(i,i)] += 1.f;

        // ---- R = E + X*O ----
        #pragma unroll
        for (int i = 0; i < 8; ++i)
            #pragma unroll
            for (int j = 0; j < 8; ++j) {
                float acc = Esym(i,j);
                #pragma unroll
                for (int k = 0; k < 8; ++k) {
                    if (k == i) continue;
                    acc = fmaf(XV(i,k), Zsym(k,j), acc);
                }
                P[i*8+j] = acc;
            }

        // ---- s squarings, ping-pong (s wave-uniform) ----
        float Q[64];
        int pairs = s >> 1;
        while (pairs--) { sq64(Q, P); sq64(P, Q); }
        if (s & 1) {
            sq64(Q, P);
            #pragma unroll
            for (int t = 0; t < 64; ++t) P[t] = Q[t];
        }
    }

    // ---- LDS-staged coalesced stores: 2 rounds of 32 floats/thread ----
    __shared__ float4 ls[256 * 8];   // 32 KB
    float4* o4base = reinterpret_cast<float4*>(out) + (size_t)bid * 4096;
    #pragma unroll
    for (int r = 0; r < 2; ++r) {
        if (r) __syncthreads();      // protect buffer reuse
        #pragma unroll
        for (int j = 0; j < 8; ++j) {
            const int jj = r*8 + j;
            ls[tid*8 + ((j + tid) & 7)] =
                make_float4(P[4*jj+0], P[4*jj+1], P[4*jj+2], P[4*jj+3]);
        }
        __syncthreads();
        #pragma unroll
        for (int k = 0; k < 8; ++k) {
            const int u = k*256 + tid;
            const int o = u >> 3, c = u & 7;   // owner thread, chunk
            o4base[o*16 + c + 8*r] = ls[o*8 + ((c + o) & 7)];
        }
    }
}

extern "C" void kernel_launch(void* const* d_in, const int* in_sizes, int n_in,
                              void* d_out, int out_size, void* d_ws, size_t ws_size,
                              hipStream_t stream) {
    const float* pos = (const float*)d_in[0];   // positions [1,1024,2]
    const float* gen = (const float*)d_in[1];   // gen_params [2,4,128,8,8]
    float* out = (float*)d_out;

    const int block = 256;
    const int grid  = NMAT / block;             // 2050, exact

    if (ws_size >= (size_t)GEN_ELEMS * sizeof(float)) {
        float* genT = (float*)d_ws;
        liere_tr_kernel<<<GEN_ELEMS / 256, 256, 0, stream>>>(gen, genT);
        liere_expm_kernel<true><<<grid, block, 0, stream>>>(pos, gen, genT, out);
    } else {
        liere_expm_kernel<false><<<grid, block, 0, stream>>>(pos, gen, nullptr, out);
    }
}

// Round 6
// 53.805 us; speedup vs baseline: 1.7362x; 1.1621x over previous
//
#include <hip/hip_runtime.h>
#include <cstdint>

// LIERE position encoder: batched expm of 8x8 skew-symmetric matrices.
// Method (Cayley-Hamilton interpolation):
//   charpoly(X) = l^8 + e1 l^6 + e2 l^4 + e3 l^2 + e4, ek elem-sym of theta_k^2
//   p_m = (-1)^m tr(Y^m)/2  (Y = X^2, eigenvalues -theta_k^2 x2 multiplicity)
//   a[0..7] = Taylor(exp, deg 36) reduced mod charpoly  (f64 scalar cascade)
//   exp(Xs) = (a0 I + a2 Y + a4 Y^2 + a6 Y^3) + Xs (a1 I + a3 Y + a5 Y^2 + a7 Y^3)
// with Xs = X/2^r so theta <= 8, then r matrix squarings (r <= 5).
constexpr int LG   = 512;
constexpr int NPOS = 1025;
constexpr int NMAT = NPOS * LG;
constexpr int GEN_ELEMS = 2 * LG * 64;   // 256 KB

__host__ __device__ constexpr int UI(int i, int j) { return i*7 - (i*(i-1))/2 + (j - i - 1); }
__host__ __device__ constexpr int SI(int i, int j) { return i*8 - (i*(i-1))/2 + (j - i); }

#define YSsym(a,b)  Ys [ (a)<=(b) ? SI(a,b) : SI(b,a) ]
#define Y2sym(a,b)  Y2s[ (a)<=(b) ? SI(a,b) : SI(b,a) ]
#define EEsym(a,b)  Zs [ (a)<=(b) ? SI(a,b) : SI(b,a) ]   // E lives in Zs
#define OOsym(a,b)  Y2s[ (a)<=(b) ? SI(a,b) : SI(b,a) ]   // O lives in Y2s
#define XV(i,k) ( (i)<(k) ? U[UI(i,k)] : -U[UI(k,i)] )

__device__ __forceinline__ void sq64(float (&D)[64], const float (&S)[64]) {
    #pragma unroll
    for (int i = 0; i < 8; ++i)
        #pragma unroll
        for (int j = 0; j < 8; ++j) {
            float acc = S[i*8+0] * S[0*8+j];
            #pragma unroll
            for (int k = 1; k < 8; ++k)
                acc = fmaf(S[i*8+k], S[k*8+j], acc);
            D[i*8+j] = acc;
        }
}

// transpose gen [2][512][64] -> genT [64][512][2]
__global__ __launch_bounds__(256)
void liere_tr_kernel(const float* __restrict__ g, float* __restrict__ gT) {
    int t = blockIdx.x * 256 + threadIdx.x;
    if (t >= GEN_ELEMS) return;
    int d  = t >> 15;
    int lg = (t >> 6) & 511;
    int e  = t & 63;
    gT[(size_t)e * 1024 + lg * 2 + d] = g[t];
}

template<bool TR>
__global__ __launch_bounds__(256)
void liere_expm_kernel(const float* __restrict__ pos,
                       const float* __restrict__ gen,
                       const float* __restrict__ genT,
                       float* __restrict__ out)
{
    const int bid = blockIdx.x, tid = threadIdx.x;
    const int n   = bid >> 1;                    // token, block-uniform
    const int lg  = ((bid & 1) << 8) | tid;

    float P[64];

    if (n == 0) {   // cls -> identity
        #pragma unroll
        for (int i = 0; i < 8; ++i)
            #pragma unroll
            for (int j = 0; j < 8; ++j)
                P[i*8+j] = (i == j) ? 1.f : 0.f;
    } else {
        const float p0 = pos[(n-1)*2 + 0];
        const float p1 = pos[(n-1)*2 + 1];

        // ---- strict-upper of X = p0*B0 + p1*B1 (-0.5 shift cancels) ----
        float U[28];
        if (TR) {
            #pragma unroll
            for (int i = 0; i < 8; ++i)
                #pragma unroll
                for (int j = i+1; j < 8; ++j) {
                    const int e = i*8 + j;
                    float2 v = *reinterpret_cast<const float2*>(
                                   genT + (size_t)e * 1024 + lg * 2);
                    U[UI(i,j)] = fmaf(p0, v.x, p1 * v.y);
                }
        } else {
            const float* g0 = gen + (size_t)lg * 64;
            const float* g1 = g0 + (size_t)LG * 64;
            #pragma unroll
            for (int i = 0; i < 8; ++i)
                #pragma unroll
                for (int j = i+1; j < 8; ++j) {
                    const int e = i*8 + j;
                    U[UI(i,j)] = fmaf(p0, g0[e], p1 * g1[e]);
                }
        }

        // ---- Y = X^2 (sym, unscaled) ----
        float Ys[36];
        #pragma unroll
        for (int i = 0; i < 8; ++i)
            #pragma unroll
            for (int j = i; j < 8; ++j) {
                float acc = 0.f;
                #pragma unroll
                for (int k = 0; k < 8; ++k) {
                    if (k == i || k == j) continue;
                    acc = fmaf(XV(i,k), XV(k,j), acc);
                }
                Ys[SI(i,j)] = acc;
            }

        // ---- Y2 = Y^2 (sym, unscaled) ----
        float Y2s[36];
        #pragma unroll
        for (int i = 0; i < 8; ++i)
            #pragma unroll
            for (int j = i; j < 8; ++j) {
                float acc = YSsym(i,0) * YSsym(0,j);
                #pragma unroll
                for (int k = 1; k < 8; ++k)
                    acc = fmaf(YSsym(i,k), YSsym(k,j), acc);
                Y2s[SI(i,j)] = acc;
            }

        // ---- traces (unscaled f32): tr(Y), tr(Y^2), tr(Y^3), tr(Y^4) ----
        float trY = 0.f;
        #pragma unroll
        for (int i = 0; i < 8; ++i) trY += Ys[SI(i,i)];
        float dYY=0.f, oYY=0.f, dY3=0.f, oY3=0.f, d44=0.f, o44=0.f;
        #pragma unroll
        for (int i = 0; i < 8; ++i)
            #pragma unroll
            for (int j = i; j < 8; ++j) {
                float y = Ys[SI(i,j)], y2 = Y2s[SI(i,j)];
                if (i == j) { dYY=fmaf(y,y,dYY); dY3=fmaf(y,y2,dY3); d44=fmaf(y2,y2,d44); }
                else        { oYY=fmaf(y,y,oYY); oY3=fmaf(y,y2,oY3); o44=fmaf(y2,y2,o44); }
            }
        const float sYY = fmaf(2.f, oYY, dYY);   // tr(Y^2)
        const float sY3 = fmaf(2.f, oY3, dY3);   // tr(Y^3)
        const float s44 = fmaf(2.f, o44, d44);   // tr(Y^4)

        // ---- theta^4 <= min(||Y2||_inf, tr(Y^4)/2); r: theta/2^r <= 8 ----
        float yb = 0.f;
        #pragma unroll
        for (int i = 0; i < 8; ++i) {
            float rs = fabsf(Y2sym(i,0));
            #pragma unroll
            for (int j = 1; j < 8; ++j) rs += fabsf(Y2sym(i,j));
            yb = fmaxf(yb, rs);
        }
        float q4 = fmaxf(fminf(yb, 0.5f * s44), 1e-30f);
        int r = (int)ceilf(0.25f * __log2f(q4) - 3.0f);
        if (r < 0) r = 0;
        if (r > 5) r = 5;

        const float r1 = __uint_as_float((uint32_t)(127 - r) << 23); // 2^-r
        const float r2 = r1 * r1;
        const float r4 = r2 * r2;
        #pragma unroll
        for (int k = 0; k < 28; ++k) U[k]   *= r1;
        #pragma unroll
        for (int k = 0; k < 36; ++k) Ys[k]  *= r2;
        #pragma unroll
        for (int k = 0; k < 36; ++k) Y2s[k] *= r4;

        // ---- Newton's identities in f64: p_m = (-1)^m tr(Y^m)/2, scaled ----
        const double R2 = (double)r2;
        const double R4 = R2 * R2;
        const double P1 = -0.5 * (double)trY * R2;
        const double P2 =  0.5 * (double)sYY * R4;
        const double P3 = -0.5 * (double)sY3 * R4 * R2;
        const double P4 =  0.5 * (double)s44 * R4 * R4;
        const double E1 = P1;
        const double E2 = 0.5 * (E1*P1 - P2);
        const double E3 = (1.0/3.0) * (E2*P1 - E1*P2 + P3);
        const double E4 = 0.25 * (E3*P1 - E2*P2 + E1*P3 - P4);

        // ---- a[0..7]: Taylor(exp, deg 36) mod charpoly (f64 cascade) ----
        double c[37];
        c[0] = 1.0;
        #pragma unroll
        for (int k = 1; k <= 36; ++k) c[k] = c[k-1] / (double)k;  // const-folded
        #pragma unroll
        for (int d = 36; d >= 8; --d) {
            double t = c[d];
            c[d-2] = fma(-E1, t, c[d-2]);
            c[d-4] = fma(-E2, t, c[d-4]);
            c[d-6] = fma(-E3, t, c[d-6]);
            c[d-8] = fma(-E4, t, c[d-8]);
        }
        float cf[8];
        #pragma unroll
        for (int k = 0; k < 8; ++k) cf[k] = (float)c[k];

        // ---- Z = Y^3 = Y * Y2 (sym: commuting polynomials in X^2) ----
        float Zs[36];
        #pragma unroll
        for (int i = 0; i < 8; ++i)
            #pragma unroll
            for (int j = i; j < 8; ++j) {
                float acc = YSsym(i,0) * Y2sym(0,j);
                #pragma unroll
                for (int k = 1; k < 8; ++k)
                    acc = fmaf(YSsym(i,k), Y2sym(k,j), acc);
                Zs[SI(i,j)] = acc;
            }

        // ---- E -> Zs, O -> Y2s (elementwise; Ys dies here) ----
        #pragma unroll
        for (int k = 0; k < 36; ++k) {
            float y = Ys[k], y2 = Y2s[k], z = Zs[k];
            Zs[k]  = fmaf(cf[6], z, fmaf(cf[4], y2, cf[2]*y));
            Y2s[k] = fmaf(cf[7], z, fmaf(cf[5], y2, cf[3]*y));
        }
        #pragma unroll
        for (int i = 0; i < 8; ++i) {
            Zs[SI(i,i)]  += cf[0];
            Y2s[SI(i,i)] += cf[1];
        }

        // ---- P = E + X*O ----
        #pragma unroll
        for (int i = 0; i < 8; ++i)
            #pragma unroll
            for (int j = 0; j < 8; ++j) {
                float acc = EEsym(i,j);
                #pragma unroll
                for (int k = 0; k < 8; ++k) {
                    if (k == i) continue;
                    acc = fmaf(XV(i,k), OOsym(k,j), acc);
                }
                P[i*8+j] = acc;
            }

        // ---- r matrix squarings (per-lane r, exec-masked loop) ----
        for (int t = 0; t < r; ++t) {
            float Q[64];
            sq64(Q, P);
            #pragma unroll
            for (int k = 0; k < 64; ++k) P[k] = Q[k];
        }
    }

    // ---- LDS-staged coalesced stores: 2 rounds of 32 floats/thread ----
    __shared__ float4 ls[256 * 8];   // 32 KB
    float4* o4base = reinterpret_cast<float4*>(out) + (size_t)bid * 4096;
    #pragma unroll
    for (int rr = 0; rr < 2; ++rr) {
        if (rr) __syncthreads();
        #pragma unroll
        for (int j = 0; j < 8; ++j) {
            const int jj = rr*8 + j;
            ls[tid*8 + ((j + tid) & 7)] =
                make_float4(P[4*jj+0], P[4*jj+1], P[4*jj+2], P[4*jj+3]);
        }
        __syncthreads();
        #pragma unroll
        for (int k = 0; k < 8; ++k) {
            const int u = k*256 + tid;
            const int o = u >> 3, cidx = u & 7;
            o4base[o*16 + cidx + 8*rr] = ls[o*8 + ((cidx + o) & 7)];
        }
    }
}

extern "C" void kernel_launch(void* const* d_in, const int* in_sizes, int n_in,
                              void* d_out, int out_size, void* d_ws, size_t ws_size,
                              hipStream_t stream) {
    const float* pos = (const float*)d_in[0];
    const float* gen = (const float*)d_in[1];
    float* out = (float*)d_out;

    const int block = 256;
    const int grid  = NMAT / block;             // 2050

    if (ws_size >= (size_t)GEN_ELEMS * sizeof(float)) {
        float* genT = (float*)d_ws;
        liere_tr_kernel<<<GEN_ELEMS / 256, 256, 0, stream>>>(gen, genT);
        liere_expm_kernel<true><<<grid, block, 0, stream>>>(pos, gen, genT, out);
    } else {
        liere_expm_kernel<false><<<grid, block, 0, stream>>>(pos, gen, nullptr, out);
    }
}

// Round 7
// 51.644 us; speedup vs baseline: 1.8089x; 1.0418x over previous
//
#include <hip/hip_runtime.h>
#include <cstdint>

// LIERE position encoder: batched expm of 8x8 skew-symmetric matrices.
// Cayley-Hamilton: exp(Xs) = deg-7 poly in Xs (charpoly from traces of Y=X^2,
// eigenvalues -theta_k^2 x2 => p_m = (-1)^m tr(Y^m)/2). Coefficients from
// Taylor(exp, deg 30) mod charpoly in an f64 scalar cascade. Xs = X/2^r with
// theta<=8 (f32 cancellation limit), then r squarings. 2^-rk folded into the
// 8 scalar coefficients so matrices stay UNscaled.
constexpr int LG   = 512;
constexpr int NPOS = 1025;
constexpr int NMAT = NPOS * LG;
constexpr int GEN_ELEMS = 2 * LG * 64;   // 256 KB

__host__ __device__ constexpr int UI(int i, int j) { return i*7 - (i*(i-1))/2 + (j - i - 1); }
__host__ __device__ constexpr int SI(int i, int j) { return i*8 - (i*(i-1))/2 + (j - i); }

#define YSsym(a,b)  Ys [ (a)<=(b) ? SI(a,b) : SI(b,a) ]
#define Y2sym(a,b)  Y2s[ (a)<=(b) ? SI(a,b) : SI(b,a) ]
#define EEsym(a,b)  Zs [ (a)<=(b) ? SI(a,b) : SI(b,a) ]   // E lives in Zs
#define OOsym(a,b)  Y2s[ (a)<=(b) ? SI(a,b) : SI(b,a) ]   // O lives in Y2s
#define XV(i,k) ( (i)<(k) ? U[UI(i,k)] : -U[UI(k,i)] )

__device__ __forceinline__ void sq64(float (&D)[64], const float (&S)[64]) {
    #pragma unroll
    for (int i = 0; i < 8; ++i)
        #pragma unroll
        for (int j = 0; j < 8; ++j) {
            float acc = S[i*8+0] * S[0*8+j];
            #pragma unroll
            for (int k = 1; k < 8; ++k)
                acc = fmaf(S[i*8+k], S[k*8+j], acc);
            D[i*8+j] = acc;
        }
}

// transpose gen [2][512][64] -> genT [64][512][2]
__global__ __launch_bounds__(256)
void liere_tr_kernel(const float* __restrict__ g, float* __restrict__ gT) {
    int t = blockIdx.x * 256 + threadIdx.x;
    if (t >= GEN_ELEMS) return;
    int d  = t >> 15;
    int lg = (t >> 6) & 511;
    int e  = t & 63;
    gT[(size_t)e * 1024 + lg * 2 + d] = g[t];
}

template<bool TR>
__global__ __launch_bounds__(256)
void liere_expm_kernel(const float* __restrict__ pos,
                       const float* __restrict__ gen,
                       const float* __restrict__ genT,
                       float* __restrict__ out)
{
    const int bid = blockIdx.x, tid = threadIdx.x;
    const int n   = bid >> 1;                    // token, block-uniform
    const int lg  = ((bid & 1) << 8) | tid;

    float P[64];

    if (n == 0) {   // cls -> identity
        #pragma unroll
        for (int i = 0; i < 8; ++i)
            #pragma unroll
            for (int j = 0; j < 8; ++j)
                P[i*8+j] = (i == j) ? 1.f : 0.f;
    } else {
        const float p0 = pos[(n-1)*2 + 0];
        const float p1 = pos[(n-1)*2 + 1];

        // ---- strict-upper of X = p0*B0 + p1*B1 (-0.5 shift cancels) ----
        float U[28];
        if (TR) {
            #pragma unroll
            for (int i = 0; i < 8; ++i)
                #pragma unroll
                for (int j = i+1; j < 8; ++j) {
                    const int e = i*8 + j;
                    float2 v = *reinterpret_cast<const float2*>(
                                   genT + (size_t)e * 1024 + lg * 2);
                    U[UI(i,j)] = fmaf(p0, v.x, p1 * v.y);
                }
        } else {
            const float* g0 = gen + (size_t)lg * 64;
            const float* g1 = g0 + (size_t)LG * 64;
            #pragma unroll
            for (int i = 0; i < 8; ++i)
                #pragma unroll
                for (int j = i+1; j < 8; ++j) {
                    const int e = i*8 + j;
                    U[UI(i,j)] = fmaf(p0, g0[e], p1 * g1[e]);
                }
        }

        // ---- Y = X^2 (sym, 36 entries; X diag is 0), UNscaled ----
        float Ys[36];
        #pragma unroll
        for (int i = 0; i < 8; ++i)
            #pragma unroll
            for (int j = i; j < 8; ++j) {
                float acc = 0.f;
                #pragma unroll
                for (int k = 0; k < 8; ++k) {
                    if (k == i || k == j) continue;
                    acc = fmaf(XV(i,k), XV(k,j), acc);
                }
                Ys[SI(i,j)] = acc;
            }

        // ---- Y2 = Y^2 (sym), UNscaled ----
        float Y2s[36];
        #pragma unroll
        for (int i = 0; i < 8; ++i)
            #pragma unroll
            for (int j = i; j < 8; ++j) {
                float acc = YSsym(i,0) * YSsym(0,j);
                #pragma unroll
                for (int k = 1; k < 8; ++k)
                    acc = fmaf(YSsym(i,k), YSsym(k,j), acc);
                Y2s[SI(i,j)] = acc;
            }

        // ---- traces (unscaled): tr(Y), tr(Y^2), tr(Y^3), tr(Y^4) ----
        float trY = 0.f;
        #pragma unroll
        for (int i = 0; i < 8; ++i) trY += Ys[SI(i,i)];
        float dYY=0.f, oYY=0.f, dY3=0.f, oY3=0.f, d44=0.f, o44=0.f;
        #pragma unroll
        for (int i = 0; i < 8; ++i)
            #pragma unroll
            for (int j = i; j < 8; ++j) {
                float y = Ys[SI(i,j)], y2 = Y2s[SI(i,j)];
                if (i == j) { dYY=fmaf(y,y,dYY); dY3=fmaf(y,y2,dY3); d44=fmaf(y2,y2,d44); }
                else        { oYY=fmaf(y,y,oYY); oY3=fmaf(y,y2,oY3); o44=fmaf(y2,y2,o44); }
            }
        const float sYY = fmaf(2.f, oYY, dYY);   // tr(Y^2)
        const float sY3 = fmaf(2.f, oY3, dY3);   // tr(Y^3)
        const float s44 = fmaf(2.f, o44, d44);   // tr(Y^4)

        // ---- theta^4 <= min(||Y2||_inf, tr(Y^4)/2); wave-uniform ----
        float yb = 0.f;
        #pragma unroll
        for (int i = 0; i < 8; ++i) {
            float rs = fabsf(Y2sym(i,0));
            #pragma unroll
            for (int j = 1; j < 8; ++j) rs += fabsf(Y2sym(i,j));
            yb = fmaxf(yb, rs);
        }
        float q4 = fmaxf(fminf(yb, 0.5f * s44), 1e-30f);
        #pragma unroll
        for (int off = 32; off >= 1; off >>= 1)
            q4 = fmaxf(q4, __shfl_xor(q4, off, 64));
        // r: theta/2^r <= 8
        int r = (int)ceilf(0.25f * __log2f(q4) - 3.0f);
        if (r < 0) r = 0;
        if (r > 5) r = 5;

        // ---- Newton's identities in f64 (scaled spectrum) ----
        const double R2 = (double)__uint_as_float((uint32_t)(127 - 2*r) << 23); // 2^-2r
        const double R4 = R2 * R2;
        const double P1 = -0.5 * (double)trY * R2;
        const double P2 =  0.5 * (double)sYY * R4;
        const double P3 = -0.5 * (double)sY3 * R4 * R2;
        const double P4 =  0.5 * (double)s44 * R4 * R4;
        const double E1 = P1;
        const double E2 = 0.5 * (E1*P1 - P2);
        const double E3 = (1.0/3.0) * (E2*P1 - E1*P2 + P3);
        const double E4 = 0.25 * (E3*P1 - E2*P2 + E1*P3 - P4);

        // ---- Taylor(exp, deg 30) mod charpoly: f64 cascade, LITERAL table ----
        double c[31] = {
            1.0, 1.0, 0.5, 0.16666666666666666, 0.041666666666666664,
            0.008333333333333333, 0.001388888888888889, 1.984126984126984e-4,
            2.48015873015873e-5, 2.7557319223985893e-6, 2.755731922398589e-7,
            2.505210838544172e-8, 2.08767569878681e-9, 1.6059043836821613e-10,
            1.1470745597729725e-11, 7.647163731819816e-13, 4.779477332387385e-14,
            2.8114572543455206e-15, 1.5619206968586225e-16, 8.22063524662433e-18,
            4.110317623312165e-19, 1.9572941063391263e-20, 8.896791392450574e-22,
            3.868170170630684e-23, 1.6117375710961184e-24, 6.446950284384474e-26,
            2.4795962632247976e-27, 9.183689863795546e-29, 3.279889237069838e-30,
            1.1309962886447716e-31, 3.7699876288159054e-33
        };
        #pragma unroll
        for (int d = 30; d >= 8; --d) {
            double t = c[d];
            c[d-2] = fma(-E1, t, c[d-2]);
            c[d-4] = fma(-E2, t, c[d-4]);
            c[d-6] = fma(-E3, t, c[d-6]);
            c[d-8] = fma(-E4, t, c[d-8]);
        }
        // fold 2^-rk into coefficients (matrices stay unscaled)
        const double W = (double)__uint_as_float((uint32_t)(127 - r) << 23);
        double wk = 1.0;
        float cf[8];
        #pragma unroll
        for (int k = 0; k < 8; ++k) { cf[k] = (float)(c[k] * wk); wk *= W; }

        // ---- Z = Y^3 = Y * Y2 (sym) ----
        float Zs[36];
        #pragma unroll
        for (int i = 0; i < 8; ++i)
            #pragma unroll
            for (int j = i; j < 8; ++j) {
                float acc = YSsym(i,0) * Y2sym(0,j);
                #pragma unroll
                for (int k = 1; k < 8; ++k)
                    acc = fmaf(YSsym(i,k), Y2sym(k,j), acc);
                Zs[SI(i,j)] = acc;
            }

        // ---- E -> Zs, O -> Y2s (elementwise; Ys dies here) ----
        #pragma unroll
        for (int k = 0; k < 36; ++k) {
            float y = Ys[k], y2 = Y2s[k], z = Zs[k];
            Zs[k]  = fmaf(cf[6], z, fmaf(cf[4], y2, cf[2]*y));
            Y2s[k] = fmaf(cf[7], z, fmaf(cf[5], y2, cf[3]*y));
        }
        #pragma unroll
        for (int i = 0; i < 8; ++i) {
            Zs[SI(i,i)]  += cf[0];
            Y2s[SI(i,i)] += cf[1];
        }

        // ---- P = E + X*O  (unscaled X; cf already carries 2^-rk) ----
        #pragma unroll
        for (int i = 0; i < 8; ++i)
            #pragma unroll
            for (int j = 0; j < 8; ++j) {
                float acc = EEsym(i,j);
                #pragma unroll
                for (int k = 0; k < 8; ++k) {
                    if (k == i) continue;
                    acc = fmaf(XV(i,k), OOsym(k,j), acc);
                }
                P[i*8+j] = acc;
            }

        // ---- r squarings, ping-pong (r wave-uniform -> scalar loop) ----
        {
            float Q[64];
            int pairs = r >> 1;
            while (pairs--) { sq64(Q, P); sq64(P, Q); }
            if (r & 1) {
                sq64(Q, P);
                #pragma unroll
                for (int t = 0; t < 64; ++t) P[t] = Q[t];
            }
        }
    }

    // ---- LDS-staged coalesced stores: 2 rounds of 32 floats/thread ----
    __shared__ float4 ls[256 * 8];   // 32 KB
    float4* o4base = reinterpret_cast<float4*>(out) + (size_t)bid * 4096;
    #pragma unroll
    for (int rr = 0; rr < 2; ++rr) {
        if (rr) __syncthreads();
        #pragma unroll
        for (int j = 0; j < 8; ++j) {
            const int jj = rr*8 + j;
            ls[tid*8 + ((j + tid) & 7)] =
                make_float4(P[4*jj+0], P[4*jj+1], P[4*jj+2], P[4*jj+3]);
        }
        __syncthreads();
        #pragma unroll
        for (int k = 0; k < 8; ++k) {
            const int u = k*256 + tid;
            const int o = u >> 3, cidx = u & 7;
            o4base[o*16 + cidx + 8*rr] = ls[o*8 + ((cidx + o) & 7)];
        }
    }
}

extern "C" void kernel_launch(void* const* d_in, const int* in_sizes, int n_in,
                              void* d_out, int out_size, void* d_ws, size_t ws_size,
                              hipStream_t stream) {
    const float* pos = (const float*)d_in[0];
    const float* gen = (const float*)d_in[1];
    float* out = (float*)d_out;

    const int block = 256;
    const int grid  = NMAT / block;             // 2050

    if (ws_size >= (size_t)GEN_ELEMS * sizeof(float)) {
        float* genT = (float*)d_ws;
        liere_tr_kernel<<<GEN_ELEMS / 256, 256, 0, stream>>>(gen, genT);
        liere_expm_kernel<true><<<grid, block, 0, stream>>>(pos, gen, genT, out);
    } else {
        liere_expm_kernel<false><<<grid, block, 0, stream>>>(pos, gen, nullptr, out);
    }
}